// Round 10
// baseline (299.617 us; speedup 1.0000x reference)
//
#include <hip/hip_runtime.h>
#include <hip/hip_bf16.h>

#define N_TOK 2048
#define DMODEL 1024
#define NEXP 8
#define FFDIM 4096
#define NMAX 2048
#define PADROWS 5120
#define TMAX 40

#define BM 128
#define BN 128
#define BK 64
#define KSPL 4

typedef __attribute__((ext_vector_type(8))) short s16x8;
typedef __attribute__((ext_vector_type(4))) float f32x4;

__device__ __forceinline__ float bf2f(ushort u) {
    union { uint i; float f; } x; x.i = ((uint)u) << 16; return x.f;
}
__device__ __forceinline__ ushort f2bf(float f) {
    union { float f; uint i; } x; x.f = f;
    uint r = x.i + 0x7fffu + ((x.i >> 16) & 1u);
    return (ushort)(r >> 16);
}

__device__ __forceinline__ void gl_lds16(const void* g, void* l) {
    __builtin_amdgcn_global_load_lds(
        (const __attribute__((address_space(1))) unsigned int*)g,
        (__attribute__((address_space(3))) unsigned int*)l, 16, 0, 0);
}

__device__ __forceinline__ float block_sum(float v, float* s4) {
    #pragma unroll
    for (int off = 32; off; off >>= 1) v += __shfl_down(v, off);
    __syncthreads();
    if ((threadIdx.x & 63) == 0) s4[threadIdx.x >> 6] = v;
    __syncthreads();
    return s4[0] + s4[1] + s4[2] + s4[3];
}

// ---------------- Router ----------------
__global__ __launch_bounds__(256)
void router_kernel(const float* __restrict__ x, const float* __restrict__ gate_w,
                   ushort* __restrict__ norm, float* __restrict__ scores,
                   int* __restrict__ cnt, int* __restrict__ lists,
                   int4* __restrict__ info, float2* __restrict__ gpair) {
    __shared__ float s4[4];
    const int n = blockIdx.x, tid = threadIdx.x;
    const float* xr = x + (size_t)n * DMODEL;
    float4 v = *(const float4*)(xr + tid * 4);

    float tot = block_sum(v.x + v.y + v.z + v.w, s4);
    float mu = tot * (1.0f / DMODEL);
    float d0 = v.x - mu, d1 = v.y - mu, d2 = v.z - mu, d3 = v.w - mu;
    float var = block_sum(d0 * d0 + d1 * d1 + d2 * d2 + d3 * d3, s4) * (1.0f / DMODEL);
    float rstd = rsqrtf(var + 1e-6f);

    ushort nb[4] = { f2bf(d0 * rstd), f2bf(d1 * rstd), f2bf(d2 * rstd), f2bf(d3 * rstd) };
    *(uint2*)(norm + (size_t)n * DMODEL + tid * 4) = *(uint2*)nb;

    float lg[NEXP];
    #pragma unroll
    for (int e = 0; e < NEXP; ++e) {
        float4 g = *(const float4*)(gate_w + (size_t)e * DMODEL + tid * 4);
        lg[e] = v.x * g.x + v.y * g.y + v.z * g.z + v.w * g.w;
    }
    #pragma unroll
    for (int e = 0; e < NEXP; ++e) lg[e] = block_sum(lg[e], s4);

    if (tid == 0) {
        float m = lg[0];
        #pragma unroll
        for (int e = 1; e < NEXP; ++e) m = fmaxf(m, lg[e]);
        float ex[NEXP], Z = 0.f;
        #pragma unroll
        for (int e = 0; e < NEXP; ++e) { ex[e] = expf(lg[e] - m); Z += ex[e]; }
        float inv = 1.0f / Z;
        float sc[NEXP];
        #pragma unroll
        for (int e = 0; e < NEXP; ++e) { sc[e] = ex[e] * inv; scores[n * NEXP + e] = sc[e]; }
        int i1 = 0;
        #pragma unroll
        for (int e = 1; e < NEXP; ++e) if (sc[e] > sc[i1]) i1 = e;
        int i2 = (i1 == 0) ? 1 : 0;
        #pragma unroll
        for (int e = 0; e < NEXP; ++e) if (e != i1 && sc[e] > sc[i2]) i2 = e;
        int s1 = atomicAdd(&cnt[i1], 1);
        lists[i1 * NMAX + s1] = n;
        int s2 = atomicAdd(&cnt[i2], 1);
        lists[i2 * NMAX + s2] = n;
        info[n] = make_int4(i1, s1, i2, s2);
        gpair[n] = make_float2(sc[i1], sc[i2]);
    }
}

// ------- Prep: aux loss + padded offsets + row-tile map -------
__global__ __launch_bounds__(256)
void prep_kernel(const float* __restrict__ scores, const int* __restrict__ cnt,
                 int* __restrict__ offs_pad, int* __restrict__ ntiles,
                 int4* __restrict__ tilemap, float* __restrict__ aux_out) {
    __shared__ float s4[4];
    __shared__ float imp[NEXP];
    float part[NEXP] = {};
    for (int i = threadIdx.x; i < N_TOK; i += 256) {
        #pragma unroll
        for (int e = 0; e < NEXP; ++e) part[e] += scores[i * NEXP + e];
    }
    #pragma unroll
    for (int e = 0; e < NEXP; ++e) {
        float s = block_sum(part[e], s4);
        if (threadIdx.x == 0) imp[e] = s;
    }
    __syncthreads();
    if (threadIdx.x == 0) {
        float aux = 0.f; int pad = 0, idx = 0;
        #pragma unroll
        for (int e = 0; e < NEXP; ++e) {
            aux += imp[e] * (float)cnt[e];
            offs_pad[e] = pad;
            int tiles = (cnt[e] + BM - 1) / BM;
            for (int t = 0; t < tiles; ++t)
                tilemap[idx++] = make_int4(e, pad + t * BM, 0, 0);
            pad += tiles * BM;
        }
        offs_pad[NEXP] = pad;
        ntiles[0] = idx;
        aux_out[0] = aux * (float)NEXP / ((float)N_TOK * (float)N_TOK);
    }
}

// ------- Gather into padded grouped layout; zero pad rows -------
__global__ __launch_bounds__(256)
void gather_kernel(const ushort* __restrict__ norm, const float* __restrict__ ln_g,
                   const float* __restrict__ ln_b, const int* __restrict__ offs_pad,
                   const int* __restrict__ cnt, const int* __restrict__ lists,
                   ushort* __restrict__ A1) {
    const int r = blockIdx.x;
    int e = 0;
    #pragma unroll
    for (int k = 1; k < NEXP; ++k) if (r >= offs_pad[k]) e = k;
    const int slot = r - offs_pad[e];
    const int t4 = threadIdx.x * 4;
    if (slot >= cnt[e]) {
        ushort z[4] = {};
        *(uint2*)(A1 + (size_t)r * DMODEL + t4) = *(uint2*)z;
        return;
    }
    const int token = lists[e * NMAX + slot];
    uint2 nbv = *(const uint2*)(norm + (size_t)token * DMODEL + t4);
    ushort ns[4]; *(uint2*)ns = nbv;
    float4 gv = *(const float4*)(ln_g + (size_t)e * DMODEL + t4);
    float4 bv = *(const float4*)(ln_b + (size_t)e * DMODEL + t4);
    ushort ob[4] = { f2bf(bf2f(ns[0]) * gv.x + bv.x), f2bf(bf2f(ns[1]) * gv.y + bv.y),
                     f2bf(bf2f(ns[2]) * gv.z + bv.z), f2bf(bf2f(ns[3]) * gv.w + bv.w) };
    *(uint2*)(A1 + (size_t)r * DMODEL + t4) = *(uint2*)ob;
}

// ------- Grouped GEMM: depth-1 pipeline, pinned issue order, raw barrier -------
// Per step: issue W(t+1) regs FIRST (8 dwordx4/thread), then A(t+1) gl_lds (4/wave)
// -> in-order vmcnt lets cvtWriteW wait only the W loads (vmcnt(4)). MFMA(buf) runs
// under both load sets. After cvt+ds_write: vmcnt(0)+lgkmcnt(0)+s_barrier (A landed
// during MFMA+cvt). sched_barrier(0) fences pin the order (R8's failure: hipcc sank
// the W loads -> VGPR 88; success indicator this round: VGPR ~130).
template<int KDIM, int NT, int KSPLT, bool RELU>
__global__ __launch_bounds__(256, 2)
void moe_gemm(const ushort* __restrict__ A, const float* __restrict__ W,
              const float* __restrict__ bias, const int* __restrict__ ntiles,
              const int4* __restrict__ tilemap, ushort* __restrict__ hout,
              float* __restrict__ yout) {
    __shared__ ushort As[2][BM * BK];   // 2 x 16 KB
    __shared__ ushort Ws[2][BN * BK];   // 2 x 16 KB
    constexpr int NOUT = NT * BN;

    const int q = (int)gridDim.x >> 3;
    const int logical = ((int)blockIdx.x & 7) * q + ((int)blockIdx.x >> 3);
    const int bt = logical % TMAX;
    int g = logical / TMAX;
    if (bt >= ntiles[0]) return;
    const int nt = g % NT;
    const int kb = g / NT;
    const int4 tm = tilemap[bt];
    const int e = tm.x, row0 = tm.y;

    const int tid = threadIdx.x, lane = tid & 63, wave = tid >> 6;
    const int wm = (wave & 1) * 64, wn = (wave >> 1) * 64;
    const int trow = lane >> 3;
    const int scol = ((lane & 7) ^ trow) * 8;

    const ushort* Agb = A + (size_t)row0 * KDIM;
    const float*  Wgb = W + ((size_t)e * NOUT + nt * BN) * KDIM;

    f32x4 acc[4][4] = {};
    float4 wr[8];

    auto loadWreg = [&](int step) {
        #pragma unroll
        for (int i = 0; i < 4; ++i) {
            int c = tid + 256 * i;
            const float* p = Wgb + (size_t)(c >> 3) * KDIM + step * BK + (c & 7) * 8;
            wr[2 * i]     = *(const float4*)p;
            wr[2 * i + 1] = *(const float4*)(p + 4);
        }
    };
    auto stageA = [&](int step, int b) {
        #pragma unroll
        for (int i = 0; i < 4; ++i) {
            int c = wave * 4 + i;
            gl_lds16(Agb + (size_t)(c * 8 + trow) * KDIM + step * BK + scol, &As[b][c * 512]);
        }
    };
    auto cvtWriteW = [&](int b) {
        #pragma unroll
        for (int i = 0; i < 4; ++i) {
            int c = tid + 256 * i;
            int row = c >> 3, col8 = (c & 7) * 8;
            union { s16x8 v; __hip_bfloat162 h2[4]; } u;
            u.h2[0] = __float22bfloat162_rn(make_float2(wr[2 * i].x, wr[2 * i].y));
            u.h2[1] = __float22bfloat162_rn(make_float2(wr[2 * i].z, wr[2 * i].w));
            u.h2[2] = __float22bfloat162_rn(make_float2(wr[2 * i + 1].x, wr[2 * i + 1].y));
            u.h2[3] = __float22bfloat162_rn(make_float2(wr[2 * i + 1].z, wr[2 * i + 1].w));
            *(s16x8*)&Ws[b][row * BK + (col8 ^ ((row & 7) << 3))] = u.v;
        }
    };
    auto mfma_phase = [&](int b) {
        #pragma unroll
        for (int kki = 0; kki < 2; ++kki) {
            const int cx = (kki * 32 + (lane >> 4) * 8) ^ ((lane & 7) << 3);
            s16x8 af[4], bfv[4];
            #pragma unroll
            for (int mi = 0; mi < 4; ++mi)
                af[mi] = *(const s16x8*)&As[b][(wm + mi * 16 + (lane & 15)) * BK + cx];
            #pragma unroll
            for (int ni = 0; ni < 4; ++ni)
                bfv[ni] = *(const s16x8*)&Ws[b][(wn + ni * 16 + (lane & 15)) * BK + cx];
            #pragma unroll
            for (int mi = 0; mi < 4; ++mi)
                #pragma unroll
                for (int ni = 0; ni < 4; ++ni)
                    acc[mi][ni] = __builtin_amdgcn_mfma_f32_16x16x32_bf16(
                        af[mi], bfv[ni], acc[mi][ni], 0, 0, 0);
        }
    };

    const int KS = KDIM / BK / KSPLT;
    const int kt0 = kb * KS;

    // prologue: fill buffer 0 (serial)
    loadWreg(kt0);
    stageA(kt0, 0);
    cvtWriteW(0);
    asm volatile("s_waitcnt vmcnt(0) lgkmcnt(0)" ::: "memory");
    __builtin_amdgcn_s_barrier();
    __builtin_amdgcn_sched_barrier(0);

    int buf = 0;
    for (int s = 0; s < KS; ++s) {
        if (s + 1 < KS) {
            loadWreg(kt0 + s + 1);              // W first (older in vmcnt order)
            __builtin_amdgcn_sched_barrier(0);
            stageA(kt0 + s + 1, buf ^ 1);       // A gl_lds (younger)
            __builtin_amdgcn_sched_barrier(0);
        }
        mfma_phase(buf);                        // under both load sets
        __builtin_amdgcn_sched_barrier(0);
        if (s + 1 < KS) cvtWriteW(buf ^ 1);     // reg deps -> waits W only (vmcnt(4))
        asm volatile("s_waitcnt vmcnt(0) lgkmcnt(0)" ::: "memory");
        __builtin_amdgcn_sched_barrier(0);
        __builtin_amdgcn_s_barrier();
        __builtin_amdgcn_sched_barrier(0);
        buf ^= 1;
    }

    if (RELU) {
        #pragma unroll
        for (int ni = 0; ni < 4; ++ni) {
            const int nn = nt * BN + wn + ni * 16 + (lane & 15);
            const float bv = bias[(size_t)e * NOUT + nn];
            #pragma unroll
            for (int mi = 0; mi < 4; ++mi)
                #pragma unroll
                for (int r = 0; r < 4; ++r) {
                    const int sl = wm + mi * 16 + ((lane >> 4) << 2) + r;
                    hout[(size_t)(row0 + sl) * NOUT + nn] =
                        f2bf(fmaxf(acc[mi][ni][r] + bv, 0.f));
                }
        }
    } else {
        #pragma unroll
        for (int ni = 0; ni < 4; ++ni) {
            const int nn = nt * BN + wn + ni * 16 + (lane & 15);
            #pragma unroll
            for (int mi = 0; mi < 4; ++mi)
                #pragma unroll
                for (int r = 0; r < 4; ++r) {
                    const int sl = wm + mi * 16 + ((lane >> 4) << 2) + r;
                    yout[((size_t)kb * PADROWS + row0 + sl) * NOUT + nn] = acc[mi][ni][r];
                }
        }
    }
}

// ------- Combine -------
__global__ __launch_bounds__(256)
void combine_kernel(const float* __restrict__ ypart, const float* __restrict__ b2,
                    const float* __restrict__ x, const int* __restrict__ offs_pad,
                    const int4* __restrict__ info, const float2* __restrict__ gpair,
                    float* __restrict__ out) {
    const int n = blockIdx.x, d = threadIdx.x * 4;
    const int4 ii = info[n];
    const float2 g = gpair[n];
    const int r1 = offs_pad[ii.x] + ii.y, r2 = offs_pad[ii.z] + ii.w;
    f32x4 y1 = {}, y2 = {};
    #pragma unroll
    for (int kb = 0; kb < KSPL; ++kb) {
        y1 += *(const f32x4*)(ypart + ((size_t)kb * PADROWS + r1) * DMODEL + d);
        y2 += *(const f32x4*)(ypart + ((size_t)kb * PADROWS + r2) * DMODEL + d);
    }
    const f32x4 b21 = *(const f32x4*)(b2 + (size_t)ii.x * DMODEL + d);
    const f32x4 b22 = *(const f32x4*)(b2 + (size_t)ii.z * DMODEL + d);
    const f32x4 xv  = *(const f32x4*)(x + (size_t)n * DMODEL + d);
    f32x4 o = g.x * (y1 + b21 + xv) + g.y * (y2 + b22 + xv);
    *(f32x4*)(out + (size_t)n * DMODEL + d) = o;
}

extern "C" void kernel_launch(void* const* d_in, const int* in_sizes, int n_in,
                              void* d_out, int out_size, void* d_ws, size_t ws_size,
                              hipStream_t stream) {
    const float* x      = (const float*)d_in[0];
    const float* gate_w = (const float*)d_in[1];
    const float* ln_g   = (const float*)d_in[2];
    const float* ln_b   = (const float*)d_in[3];
    const float* w1     = (const float*)d_in[4];
    const float* b1     = (const float*)d_in[5];
    const float* w2     = (const float*)d_in[6];
    const float* b2     = (const float*)d_in[7];
    float* out = (float*)d_out;

    char* w = (char*)d_ws;
    int*    cnt      = (int*)(w + 0);
    int*    offs_pad = (int*)(w + 64);
    int*    ntiles   = (int*)(w + 128);
    int4*   tilemap  = (int4*)(w + 192);
    int*    lists    = (int*)(w + 1024);
    float*  scores   = (float*)(w + 66560);
    int4*   info     = (int4*)(w + 132096);
    float2* gpair    = (float2*)(w + 164864);
    ushort* norm     = (ushort*)(w + 181248);
    ushort* A1       = (ushort*)(w + 4375552);
    ushort* h        = (ushort*)(w + 14861312);
    float*  ypart    = (float*)(w + 56804352);

    hipMemsetAsync(cnt, 0, 64, stream);

    router_kernel<<<N_TOK, 256, 0, stream>>>(x, gate_w, norm, scores, cnt, lists, info, gpair);
    prep_kernel<<<1, 256, 0, stream>>>(scores, cnt, offs_pad, ntiles, tilemap,
                                       out + (size_t)N_TOK * DMODEL);
    gather_kernel<<<PADROWS, 256, 0, stream>>>(norm, ln_g, ln_b, offs_pad, cnt, lists, A1);
    moe_gemm<DMODEL, FFDIM / BN, 1, true><<<TMAX * (FFDIM / BN), 256, 0, stream>>>(
        A1, w1, b1, ntiles, tilemap, h, nullptr);
    moe_gemm<FFDIM, DMODEL / BN, KSPL, false><<<TMAX * (DMODEL / BN) * KSPL, 256, 0, stream>>>(
        h, w2, nullptr, ntiles, tilemap, nullptr, ypart);
    combine_kernel<<<N_TOK, 256, 0, stream>>>(ypart, b2, x, offs_pad, info, gpair, out);
}

// Round 11
// 287.843 us; speedup vs baseline: 1.0409x; 1.0409x over previous
//
#include <hip/hip_runtime.h>
#include <hip/hip_bf16.h>

#define N_TOK 2048
#define DMODEL 1024
#define NEXP 8
#define FFDIM 4096
#define NMAX 2048
#define PADROWS 5120
#define TMAX 40

#define BM 128
#define BN 128
#define BK 64
#define KSPL 4

typedef __attribute__((ext_vector_type(8))) short s16x8;
typedef __attribute__((ext_vector_type(4))) float f32x4;

__device__ __forceinline__ float bf2f(ushort u) {
    union { uint i; float f; } x; x.i = ((uint)u) << 16; return x.f;
}
__device__ __forceinline__ ushort f2bf(float f) {
    union { float f; uint i; } x; x.f = f;
    uint r = x.i + 0x7fffu + ((x.i >> 16) & 1u);
    return (ushort)(r >> 16);
}

__device__ __forceinline__ void gl_lds16(const void* g, void* l) {
    __builtin_amdgcn_global_load_lds(
        (const __attribute__((address_space(1))) unsigned int*)g,
        (__attribute__((address_space(3))) unsigned int*)l, 16, 0, 0);
}

// pinned 16B global load: compiler cannot sink/rematerialize an asm def.
// NOTE: no waitcnt is auto-inserted for asm loads -- caller must s_waitcnt.
__device__ __forceinline__ float4 gload_x4(const float* p) {
    float4 r;
    asm volatile("global_load_dwordx4 %0, %1, off" : "=v"(r) : "v"(p));
    return r;
}

__device__ __forceinline__ float block_sum(float v, float* s4) {
    #pragma unroll
    for (int off = 32; off; off >>= 1) v += __shfl_down(v, off);
    __syncthreads();
    if ((threadIdx.x & 63) == 0) s4[threadIdx.x >> 6] = v;
    __syncthreads();
    return s4[0] + s4[1] + s4[2] + s4[3];
}

// ---------------- Router ----------------
__global__ __launch_bounds__(256)
void router_kernel(const float* __restrict__ x, const float* __restrict__ gate_w,
                   ushort* __restrict__ norm, float* __restrict__ scores,
                   int* __restrict__ cnt, int* __restrict__ lists,
                   int4* __restrict__ info, float2* __restrict__ gpair) {
    __shared__ float s4[4];
    const int n = blockIdx.x, tid = threadIdx.x;
    const float* xr = x + (size_t)n * DMODEL;
    float4 v = *(const float4*)(xr + tid * 4);

    float tot = block_sum(v.x + v.y + v.z + v.w, s4);
    float mu = tot * (1.0f / DMODEL);
    float d0 = v.x - mu, d1 = v.y - mu, d2 = v.z - mu, d3 = v.w - mu;
    float var = block_sum(d0 * d0 + d1 * d1 + d2 * d2 + d3 * d3, s4) * (1.0f / DMODEL);
    float rstd = rsqrtf(var + 1e-6f);

    ushort nb[4] = { f2bf(d0 * rstd), f2bf(d1 * rstd), f2bf(d2 * rstd), f2bf(d3 * rstd) };
    *(uint2*)(norm + (size_t)n * DMODEL + tid * 4) = *(uint2*)nb;

    float lg[NEXP];
    #pragma unroll
    for (int e = 0; e < NEXP; ++e) {
        float4 g = *(const float4*)(gate_w + (size_t)e * DMODEL + tid * 4);
        lg[e] = v.x * g.x + v.y * g.y + v.z * g.z + v.w * g.w;
    }
    #pragma unroll
    for (int e = 0; e < NEXP; ++e) lg[e] = block_sum(lg[e], s4);

    if (tid == 0) {
        float m = lg[0];
        #pragma unroll
        for (int e = 1; e < NEXP; ++e) m = fmaxf(m, lg[e]);
        float ex[NEXP], Z = 0.f;
        #pragma unroll
        for (int e = 0; e < NEXP; ++e) { ex[e] = expf(lg[e] - m); Z += ex[e]; }
        float inv = 1.0f / Z;
        float sc[NEXP];
        #pragma unroll
        for (int e = 0; e < NEXP; ++e) { sc[e] = ex[e] * inv; scores[n * NEXP + e] = sc[e]; }
        int i1 = 0;
        #pragma unroll
        for (int e = 1; e < NEXP; ++e) if (sc[e] > sc[i1]) i1 = e;
        int i2 = (i1 == 0) ? 1 : 0;
        #pragma unroll
        for (int e = 0; e < NEXP; ++e) if (e != i1 && sc[e] > sc[i2]) i2 = e;
        int s1 = atomicAdd(&cnt[i1], 1);
        lists[i1 * NMAX + s1] = n;
        int s2 = atomicAdd(&cnt[i2], 1);
        lists[i2 * NMAX + s2] = n;
        info[n] = make_int4(i1, s1, i2, s2);
        gpair[n] = make_float2(sc[i1], sc[i2]);
    }
}

// ------- Prep: aux loss + padded offsets + row-tile map -------
__global__ __launch_bounds__(256)
void prep_kernel(const float* __restrict__ scores, const int* __restrict__ cnt,
                 int* __restrict__ offs_pad, int* __restrict__ ntiles,
                 int4* __restrict__ tilemap, float* __restrict__ aux_out) {
    __shared__ float s4[4];
    __shared__ float imp[NEXP];
    float part[NEXP] = {};
    for (int i = threadIdx.x; i < N_TOK; i += 256) {
        #pragma unroll
        for (int e = 0; e < NEXP; ++e) part[e] += scores[i * NEXP + e];
    }
    #pragma unroll
    for (int e = 0; e < NEXP; ++e) {
        float s = block_sum(part[e], s4);
        if (threadIdx.x == 0) imp[e] = s;
    }
    __syncthreads();
    if (threadIdx.x == 0) {
        float aux = 0.f; int pad = 0, idx = 0;
        #pragma unroll
        for (int e = 0; e < NEXP; ++e) {
            aux += imp[e] * (float)cnt[e];
            offs_pad[e] = pad;
            int tiles = (cnt[e] + BM - 1) / BM;
            for (int t = 0; t < tiles; ++t)
                tilemap[idx++] = make_int4(e, pad + t * BM, 0, 0);
            pad += tiles * BM;
        }
        offs_pad[NEXP] = pad;
        ntiles[0] = idx;
        aux_out[0] = aux * (float)NEXP / ((float)N_TOK * (float)N_TOK);
    }
}

// ------- Gather into padded grouped layout; zero pad rows -------
__global__ __launch_bounds__(256)
void gather_kernel(const ushort* __restrict__ norm, const float* __restrict__ ln_g,
                   const float* __restrict__ ln_b, const int* __restrict__ offs_pad,
                   const int* __restrict__ cnt, const int* __restrict__ lists,
                   ushort* __restrict__ A1) {
    const int r = blockIdx.x;
    int e = 0;
    #pragma unroll
    for (int k = 1; k < NEXP; ++k) if (r >= offs_pad[k]) e = k;
    const int slot = r - offs_pad[e];
    const int t4 = threadIdx.x * 4;
    if (slot >= cnt[e]) {
        ushort z[4] = {};
        *(uint2*)(A1 + (size_t)r * DMODEL + t4) = *(uint2*)z;
        return;
    }
    const int token = lists[e * NMAX + slot];
    uint2 nbv = *(const uint2*)(norm + (size_t)token * DMODEL + t4);
    ushort ns[4]; *(uint2*)ns = nbv;
    float4 gv = *(const float4*)(ln_g + (size_t)e * DMODEL + t4);
    float4 bv = *(const float4*)(ln_b + (size_t)e * DMODEL + t4);
    ushort ob[4] = { f2bf(bf2f(ns[0]) * gv.x + bv.x), f2bf(bf2f(ns[1]) * gv.y + bv.y),
                     f2bf(bf2f(ns[2]) * gv.z + bv.z), f2bf(bf2f(ns[3]) * gv.w + bv.w) };
    *(uint2*)(A1 + (size_t)r * DMODEL + t4) = *(uint2*)ob;
}

// ------- Grouped GEMM: depth-1 pipeline with ASM-PINNED W loads -------
// Per step (single basic block, no ifs -- clamped prefetch index):
//   issue W(t+1) x8 inline-asm dwordx4 (oldest), A(t+1) x4 gl_lds (youngest)
//   MFMA(t) on buf                       <- both load sets in flight underneath
//   s_waitcnt vmcnt(4) + sched_barrier   <- W landed; A may stay outstanding
//   cvt+swizzled ds_write W(t+1)->buf^1
//   s_waitcnt vmcnt(0) lgkmcnt(0); s_barrier
template<int KDIM, int NT, int KSPLT, bool RELU>
__global__ __launch_bounds__(256, 2)
void moe_gemm(const ushort* __restrict__ A, const float* __restrict__ W,
              const float* __restrict__ bias, const int* __restrict__ ntiles,
              const int4* __restrict__ tilemap, ushort* __restrict__ hout,
              float* __restrict__ yout) {
    __shared__ ushort As[2][BM * BK];   // 2 x 16 KB
    __shared__ ushort Ws[2][BN * BK];   // 2 x 16 KB
    constexpr int NOUT = NT * BN;

    const int q = (int)gridDim.x >> 3;
    const int logical = ((int)blockIdx.x & 7) * q + ((int)blockIdx.x >> 3);
    const int bt = logical % TMAX;
    int g = logical / TMAX;
    if (bt >= ntiles[0]) return;
    const int nt = g % NT;
    const int kb = g / NT;
    const int4 tm = tilemap[bt];
    const int e = tm.x, row0 = tm.y;

    const int tid = threadIdx.x, lane = tid & 63, wave = tid >> 6;
    const int wm = (wave & 1) * 64, wn = (wave >> 1) * 64;
    const int trow = lane >> 3;
    const int scol = ((lane & 7) ^ trow) * 8;

    const ushort* Agb = A + (size_t)row0 * KDIM;
    const float*  Wgb = W + ((size_t)e * NOUT + nt * BN) * KDIM;

    f32x4 acc[4][4] = {};
    float4 wr[8];

    auto loadWreg = [&](int step) {     // PINNED: inline-asm issue
        #pragma unroll
        for (int i = 0; i < 4; ++i) {
            int c = tid + 256 * i;
            const float* p = Wgb + (size_t)(c >> 3) * KDIM + step * BK + (c & 7) * 8;
            wr[2 * i]     = gload_x4(p);
            wr[2 * i + 1] = gload_x4(p + 4);
        }
    };
    auto stageA = [&](int step, int b) {
        #pragma unroll
        for (int i = 0; i < 4; ++i) {
            int c = wave * 4 + i;
            gl_lds16(Agb + (size_t)(c * 8 + trow) * KDIM + step * BK + scol, &As[b][c * 512]);
        }
    };
    auto cvtWriteW = [&](int b) {
        #pragma unroll
        for (int i = 0; i < 4; ++i) {
            int c = tid + 256 * i;
            int row = c >> 3, col8 = (c & 7) * 8;
            union { s16x8 v; __hip_bfloat162 h2[4]; } u;
            u.h2[0] = __float22bfloat162_rn(make_float2(wr[2 * i].x, wr[2 * i].y));
            u.h2[1] = __float22bfloat162_rn(make_float2(wr[2 * i].z, wr[2 * i].w));
            u.h2[2] = __float22bfloat162_rn(make_float2(wr[2 * i + 1].x, wr[2 * i + 1].y));
            u.h2[3] = __float22bfloat162_rn(make_float2(wr[2 * i + 1].z, wr[2 * i + 1].w));
            *(s16x8*)&Ws[b][row * BK + (col8 ^ ((row & 7) << 3))] = u.v;
        }
    };
    auto mfma_phase = [&](int b) {
        #pragma unroll
        for (int kki = 0; kki < 2; ++kki) {
            const int cx = (kki * 32 + (lane >> 4) * 8) ^ ((lane & 7) << 3);
            s16x8 af[4], bfv[4];
            #pragma unroll
            for (int mi = 0; mi < 4; ++mi)
                af[mi] = *(const s16x8*)&As[b][(wm + mi * 16 + (lane & 15)) * BK + cx];
            #pragma unroll
            for (int ni = 0; ni < 4; ++ni)
                bfv[ni] = *(const s16x8*)&Ws[b][(wn + ni * 16 + (lane & 15)) * BK + cx];
            #pragma unroll
            for (int mi = 0; mi < 4; ++mi)
                #pragma unroll
                for (int ni = 0; ni < 4; ++ni)
                    acc[mi][ni] = __builtin_amdgcn_mfma_f32_16x16x32_bf16(
                        af[mi], bfv[ni], acc[mi][ni], 0, 0, 0);
        }
    };

    const int KS = KDIM / BK / KSPLT;
    const int kt0 = kb * KS;

    // prologue: fill buffer 0 (W pinned loads -> vmcnt(4) leaves A outstanding)
    loadWreg(kt0);
    stageA(kt0, 0);
    asm volatile("s_waitcnt vmcnt(4)" ::: "memory");
    __builtin_amdgcn_sched_barrier(0);
    cvtWriteW(0);
    asm volatile("s_waitcnt vmcnt(0) lgkmcnt(0)" ::: "memory");
    __builtin_amdgcn_s_barrier();
    __builtin_amdgcn_sched_barrier(0);

    int buf = 0;
    for (int s = 0; s < KS; ++s) {
        const int nxt = (s + 1 < KS) ? (kt0 + s + 1) : (kt0 + s);  // clamped, branchless
        loadWreg(nxt);                       // 8 pinned asm loads (oldest)
        __builtin_amdgcn_sched_barrier(0);
        stageA(nxt, buf ^ 1);                // 4 gl_lds (youngest)
        __builtin_amdgcn_sched_barrier(0);
        mfma_phase(buf);                     // runs under both load sets
        __builtin_amdgcn_sched_barrier(0);
        asm volatile("s_waitcnt vmcnt(4)" ::: "memory");   // W done; A in flight
        __builtin_amdgcn_sched_barrier(0);
        cvtWriteW(buf ^ 1);
        asm volatile("s_waitcnt vmcnt(0) lgkmcnt(0)" ::: "memory");
        __builtin_amdgcn_s_barrier();
        __builtin_amdgcn_sched_barrier(0);
        buf ^= 1;
    }

    if (RELU) {
        #pragma unroll
        for (int ni = 0; ni < 4; ++ni) {
            const int nn = nt * BN + wn + ni * 16 + (lane & 15);
            const float bv = bias[(size_t)e * NOUT + nn];
            #pragma unroll
            for (int mi = 0; mi < 4; ++mi)
                #pragma unroll
                for (int r = 0; r < 4; ++r) {
                    const int sl = wm + mi * 16 + ((lane >> 4) << 2) + r;
                    hout[(size_t)(row0 + sl) * NOUT + nn] =
                        f2bf(fmaxf(acc[mi][ni][r] + bv, 0.f));
                }
        }
    } else {
        #pragma unroll
        for (int ni = 0; ni < 4; ++ni) {
            const int nn = nt * BN + wn + ni * 16 + (lane & 15);
            #pragma unroll
            for (int mi = 0; mi < 4; ++mi)
                #pragma unroll
                for (int r = 0; r < 4; ++r) {
                    const int sl = wm + mi * 16 + ((lane >> 4) << 2) + r;
                    yout[((size_t)kb * PADROWS + row0 + sl) * NOUT + nn] = acc[mi][ni][r];
                }
        }
    }
}

// ------- Combine -------
__global__ __launch_bounds__(256)
void combine_kernel(const float* __restrict__ ypart, const float* __restrict__ b2,
                    const float* __restrict__ x, const int* __restrict__ offs_pad,
                    const int4* __restrict__ info, const float2* __restrict__ gpair,
                    float* __restrict__ out) {
    const int n = blockIdx.x, d = threadIdx.x * 4;
    const int4 ii = info[n];
    const float2 g = gpair[n];
    const int r1 = offs_pad[ii.x] + ii.y, r2 = offs_pad[ii.z] + ii.w;
    f32x4 y1 = {}, y2 = {};
    #pragma unroll
    for (int kb = 0; kb < KSPL; ++kb) {
        y1 += *(const f32x4*)(ypart + ((size_t)kb * PADROWS + r1) * DMODEL + d);
        y2 += *(const f32x4*)(ypart + ((size_t)kb * PADROWS + r2) * DMODEL + d);
    }
    const f32x4 b21 = *(const f32x4*)(b2 + (size_t)ii.x * DMODEL + d);
    const f32x4 b22 = *(const f32x4*)(b2 + (size_t)ii.z * DMODEL + d);
    const f32x4 xv  = *(const f32x4*)(x + (size_t)n * DMODEL + d);
    f32x4 o = g.x * (y1 + b21 + xv) + g.y * (y2 + b22 + xv);
    *(f32x4*)(out + (size_t)n * DMODEL + d) = o;
}

extern "C" void kernel_launch(void* const* d_in, const int* in_sizes, int n_in,
                              void* d_out, int out_size, void* d_ws, size_t ws_size,
                              hipStream_t stream) {
    const float* x      = (const float*)d_in[0];
    const float* gate_w = (const float*)d_in[1];
    const float* ln_g   = (const float*)d_in[2];
    const float* ln_b   = (const float*)d_in[3];
    const float* w1     = (const float*)d_in[4];
    const float* b1     = (const float*)d_in[5];
    const float* w2     = (const float*)d_in[6];
    const float* b2     = (const float*)d_in[7];
    float* out = (float*)d_out;

    char* w = (char*)d_ws;
    int*    cnt      = (int*)(w + 0);
    int*    offs_pad = (int*)(w + 64);
    int*    ntiles   = (int*)(w + 128);
    int4*   tilemap  = (int4*)(w + 192);
    int*    lists    = (int*)(w + 1024);
    float*  scores   = (float*)(w + 66560);
    int4*   info     = (int4*)(w + 132096);
    float2* gpair    = (float2*)(w + 164864);
    ushort* norm     = (ushort*)(w + 181248);
    ushort* A1       = (ushort*)(w + 4375552);
    ushort* h        = (ushort*)(w + 14861312);
    float*  ypart    = (float*)(w + 56804352);

    hipMemsetAsync(cnt, 0, 64, stream);

    router_kernel<<<N_TOK, 256, 0, stream>>>(x, gate_w, norm, scores, cnt, lists, info, gpair);
    prep_kernel<<<1, 256, 0, stream>>>(scores, cnt, offs_pad, ntiles, tilemap,
                                       out + (size_t)N_TOK * DMODEL);
    gather_kernel<<<PADROWS, 256, 0, stream>>>(norm, ln_g, ln_b, offs_pad, cnt, lists, A1);
    moe_gemm<DMODEL, FFDIM / BN, 1, true><<<TMAX * (FFDIM / BN), 256, 0, stream>>>(
        A1, w1, b1, ntiles, tilemap, h, nullptr);
    moe_gemm<FFDIM, DMODEL / BN, KSPL, false><<<TMAX * (DMODEL / BN) * KSPL, 256, 0, stream>>>(
        h, w2, nullptr, ntiles, tilemap, nullptr, ypart);
    combine_kernel<<<N_TOK, 256, 0, stream>>>(ypart, b2, x, offs_pad, info, gpair, out);
}

// Round 12
// 274.482 us; speedup vs baseline: 1.0916x; 1.0487x over previous
//
#include <hip/hip_runtime.h>
#include <hip/hip_bf16.h>

#define N_TOK 2048
#define DMODEL 1024
#define NEXP 8
#define FFDIM 4096
#define NMAX 2048
#define PADROWS 5120
#define TMAX 40

#define BM 128
#define BN 128
#define BK 64
#define KSPL 4

typedef __attribute__((ext_vector_type(8))) short s16x8;
typedef __attribute__((ext_vector_type(4))) float f32x4;

__device__ __forceinline__ float bf2f(ushort u) {
    union { uint i; float f; } x; x.i = ((uint)u) << 16; return x.f;
}
__device__ __forceinline__ ushort f2bf(float f) {
    union { float f; uint i; } x; x.f = f;
    uint r = x.i + 0x7fffu + ((x.i >> 16) & 1u);
    return (ushort)(r >> 16);
}

__device__ __forceinline__ void gl_lds16(const void* g, void* l) {
    __builtin_amdgcn_global_load_lds(
        (const __attribute__((address_space(1))) unsigned int*)g,
        (__attribute__((address_space(3))) unsigned int*)l, 16, 0, 0);
}

__device__ __forceinline__ float block_sum(float v, float* s4) {
    #pragma unroll
    for (int off = 32; off; off >>= 1) v += __shfl_down(v, off);
    __syncthreads();
    if ((threadIdx.x & 63) == 0) s4[threadIdx.x >> 6] = v;
    __syncthreads();
    return s4[0] + s4[1] + s4[2] + s4[3];
}

// ---------------- Router ----------------
__global__ __launch_bounds__(256)
void router_kernel(const float* __restrict__ x, const float* __restrict__ gate_w,
                   ushort* __restrict__ norm, float* __restrict__ scores,
                   int* __restrict__ cnt, int* __restrict__ lists,
                   int4* __restrict__ info, float2* __restrict__ gpair) {
    __shared__ float s4[4];
    const int n = blockIdx.x, tid = threadIdx.x;
    const float* xr = x + (size_t)n * DMODEL;
    float4 v = *(const float4*)(xr + tid * 4);

    float tot = block_sum(v.x + v.y + v.z + v.w, s4);
    float mu = tot * (1.0f / DMODEL);
    float d0 = v.x - mu, d1 = v.y - mu, d2 = v.z - mu, d3 = v.w - mu;
    float var = block_sum(d0 * d0 + d1 * d1 + d2 * d2 + d3 * d3, s4) * (1.0f / DMODEL);
    float rstd = rsqrtf(var + 1e-6f);

    ushort nb[4] = { f2bf(d0 * rstd), f2bf(d1 * rstd), f2bf(d2 * rstd), f2bf(d3 * rstd) };
    *(uint2*)(norm + (size_t)n * DMODEL + tid * 4) = *(uint2*)nb;

    float lg[NEXP];
    #pragma unroll
    for (int e = 0; e < NEXP; ++e) {
        float4 g = *(const float4*)(gate_w + (size_t)e * DMODEL + tid * 4);
        lg[e] = v.x * g.x + v.y * g.y + v.z * g.z + v.w * g.w;
    }
    #pragma unroll
    for (int e = 0; e < NEXP; ++e) lg[e] = block_sum(lg[e], s4);

    if (tid == 0) {
        float m = lg[0];
        #pragma unroll
        for (int e = 1; e < NEXP; ++e) m = fmaxf(m, lg[e]);
        float ex[NEXP], Z = 0.f;
        #pragma unroll
        for (int e = 0; e < NEXP; ++e) { ex[e] = expf(lg[e] - m); Z += ex[e]; }
        float inv = 1.0f / Z;
        float sc[NEXP];
        #pragma unroll
        for (int e = 0; e < NEXP; ++e) { sc[e] = ex[e] * inv; scores[n * NEXP + e] = sc[e]; }
        int i1 = 0;
        #pragma unroll
        for (int e = 1; e < NEXP; ++e) if (sc[e] > sc[i1]) i1 = e;
        int i2 = (i1 == 0) ? 1 : 0;
        #pragma unroll
        for (int e = 0; e < NEXP; ++e) if (e != i1 && sc[e] > sc[i2]) i2 = e;
        int s1 = atomicAdd(&cnt[i1], 1);
        lists[i1 * NMAX + s1] = n;
        int s2 = atomicAdd(&cnt[i2], 1);
        lists[i2 * NMAX + s2] = n;
        info[n] = make_int4(i1, s1, i2, s2);
        gpair[n] = make_float2(sc[i1], sc[i2]);
    }
}

// ------- Prep: aux loss + padded offsets + row-tile map -------
__global__ __launch_bounds__(256)
void prep_kernel(const float* __restrict__ scores, const int* __restrict__ cnt,
                 int* __restrict__ offs_pad, int* __restrict__ ntiles,
                 int4* __restrict__ tilemap, float* __restrict__ aux_out) {
    __shared__ float s4[4];
    __shared__ float imp[NEXP];
    float part[NEXP] = {};
    for (int i = threadIdx.x; i < N_TOK; i += 256) {
        #pragma unroll
        for (int e = 0; e < NEXP; ++e) part[e] += scores[i * NEXP + e];
    }
    #pragma unroll
    for (int e = 0; e < NEXP; ++e) {
        float s = block_sum(part[e], s4);
        if (threadIdx.x == 0) imp[e] = s;
    }
    __syncthreads();
    if (threadIdx.x == 0) {
        float aux = 0.f; int pad = 0, idx = 0;
        #pragma unroll
        for (int e = 0; e < NEXP; ++e) {
            aux += imp[e] * (float)cnt[e];
            offs_pad[e] = pad;
            int tiles = (cnt[e] + BM - 1) / BM;
            for (int t = 0; t < tiles; ++t)
                tilemap[idx++] = make_int4(e, pad + t * BM, 0, 0);
            pad += tiles * BM;
        }
        offs_pad[NEXP] = pad;
        ntiles[0] = idx;
        aux_out[0] = aux * (float)NEXP / ((float)N_TOK * (float)N_TOK);
    }
}

// ------- Gather into padded grouped layout; zero pad rows -------
__global__ __launch_bounds__(256)
void gather_kernel(const ushort* __restrict__ norm, const float* __restrict__ ln_g,
                   const float* __restrict__ ln_b, const int* __restrict__ offs_pad,
                   const int* __restrict__ cnt, const int* __restrict__ lists,
                   ushort* __restrict__ A1) {
    const int r = blockIdx.x;
    int e = 0;
    #pragma unroll
    for (int k = 1; k < NEXP; ++k) if (r >= offs_pad[k]) e = k;
    const int slot = r - offs_pad[e];
    const int t4 = threadIdx.x * 4;
    if (slot >= cnt[e]) {
        ushort z[4] = {};
        *(uint2*)(A1 + (size_t)r * DMODEL + t4) = *(uint2*)z;
        return;
    }
    const int token = lists[e * NMAX + slot];
    uint2 nbv = *(const uint2*)(norm + (size_t)token * DMODEL + t4);
    ushort ns[4]; *(uint2*)ns = nbv;
    float4 gv = *(const float4*)(ln_g + (size_t)e * DMODEL + t4);
    float4 bv = *(const float4*)(ln_b + (size_t)e * DMODEL + t4);
    ushort ob[4] = { f2bf(bf2f(ns[0]) * gv.x + bv.x), f2bf(bf2f(ns[1]) * gv.y + bv.y),
                     f2bf(bf2f(ns[2]) * gv.z + bv.z), f2bf(bf2f(ns[3]) * gv.w + bv.w) };
    *(uint2*)(A1 + (size_t)r * DMODEL + t4) = *(uint2*)ob;
}

// ------- Grouped GEMM: R7-proven serial step; NT-FASTEST decode for L2 locality -----
// Decode change vs R7: g = logical % (NT*KSPLT), bt = logical / (NT*KSPLT).
// An XCD's contiguous logical chunk is now ~5 row-tiles x all n-tiles: A panels
// become L2-resident (read 32x), concurrent same-W blocks share one L2 fill.
template<int KDIM, int NT, int KSPLT, bool RELU>
__global__ __launch_bounds__(256, 3)
void moe_gemm(const ushort* __restrict__ A, const float* __restrict__ W,
              const float* __restrict__ bias, const int* __restrict__ ntiles,
              const int4* __restrict__ tilemap, ushort* __restrict__ hout,
              float* __restrict__ yout) {
    __shared__ ushort As[BM * BK];      // 16 KB bf16 A tile
    __shared__ float  Wsf[BN * BK];     // 32 KB f32 W tile
    constexpr int NOUT = NT * BN;
    constexpr int GDIM = NT * KSPLT;

    const int q = (int)gridDim.x >> 3;
    const int logical = ((int)blockIdx.x & 7) * q + ((int)blockIdx.x >> 3);
    const int g = logical % GDIM;       // nt/kb fastest -> XCD chunk = few bt x all nt
    const int bt = logical / GDIM;
    if (bt >= ntiles[0]) return;
    const int nt = g % NT;
    const int kb = g / NT;
    const int4 tm = tilemap[bt];
    const int e = tm.x, row0 = tm.y;

    const int tid = threadIdx.x, lane = tid & 63, wave = tid >> 6;
    const int wm = (wave & 1) * 64, wn = (wave >> 1) * 64;
    const int trow = lane >> 3;
    const int scol = ((lane & 7) ^ trow) * 8;   // A: pre-swizzled source column

    const ushort* Agb = A + (size_t)row0 * KDIM;
    const float*  Wgb = W + ((size_t)e * NOUT + nt * BN) * KDIM;

    const int wrow  = (lane >> 4);
    const int wchnk = (lane & 15);

    f32x4 acc[4][4] = {};

    auto stageA = [&](int step) {
        #pragma unroll
        for (int i = 0; i < 4; ++i) {
            int c = wave * 4 + i;
            gl_lds16(Agb + (size_t)(c * 8 + trow) * KDIM + step * BK + scol, &As[c * 512]);
        }
    };
    auto stageW = [&](int step) {
        #pragma unroll
        for (int i = 0; i < 8; ++i) {
            int r0 = wave * 32 + i * 4;
            int row = r0 + wrow;
            int chunk = wchnk ^ (row & 7);
            gl_lds16(Wgb + (size_t)row * KDIM + step * BK + chunk * 4, &Wsf[r0 * 64]);
        }
    };
    auto readW = [&](int ni, int kki) -> s16x8 {
        const int row = wn + ni * 16 + (lane & 15);
        const int x = row & 7;
        const int cb = kki * 8 + (lane >> 4) * 2;
        const float4 f0 = *(const float4*)&Wsf[row * 64 + ((cb ^ x) << 2)];
        const float4 f1 = *(const float4*)&Wsf[row * 64 + (((cb + 1) ^ x) << 2)];
        union { s16x8 v; __hip_bfloat162 h2[4]; } u;
        u.h2[0] = __float22bfloat162_rn(make_float2(f0.x, f0.y));
        u.h2[1] = __float22bfloat162_rn(make_float2(f0.z, f0.w));
        u.h2[2] = __float22bfloat162_rn(make_float2(f1.x, f1.y));
        u.h2[3] = __float22bfloat162_rn(make_float2(f1.z, f1.w));
        return u.v;
    };
    auto mfma_phase = [&]() {
        #pragma unroll
        for (int kki = 0; kki < 2; ++kki) {
            const int cx = (kki * 32 + (lane >> 4) * 8) ^ ((lane & 7) << 3);
            s16x8 af[4], bfv[4];
            #pragma unroll
            for (int mi = 0; mi < 4; ++mi)
                af[mi] = *(const s16x8*)&As[(wm + mi * 16 + (lane & 15)) * BK + cx];
            #pragma unroll
            for (int ni = 0; ni < 4; ++ni)
                bfv[ni] = readW(ni, kki);
            #pragma unroll
            for (int mi = 0; mi < 4; ++mi)
                #pragma unroll
                for (int ni = 0; ni < 4; ++ni)
                    acc[mi][ni] = __builtin_amdgcn_mfma_f32_16x16x32_bf16(
                        af[mi], bfv[ni], acc[mi][ni], 0, 0, 0);
        }
    };

    const int KS = KDIM / BK / KSPLT;
    const int kt0 = kb * KS;

    for (int s = 0; s < KS; ++s) {
        stageA(kt0 + s);
        stageW(kt0 + s);
        __syncthreads();
        mfma_phase();
        __syncthreads();
    }

    if (RELU) {
        #pragma unroll
        for (int ni = 0; ni < 4; ++ni) {
            const int nn = nt * BN + wn + ni * 16 + (lane & 15);
            const float bv = bias[(size_t)e * NOUT + nn];
            #pragma unroll
            for (int mi = 0; mi < 4; ++mi)
                #pragma unroll
                for (int r = 0; r < 4; ++r) {
                    const int sl = wm + mi * 16 + ((lane >> 4) << 2) + r;
                    hout[(size_t)(row0 + sl) * NOUT + nn] =
                        f2bf(fmaxf(acc[mi][ni][r] + bv, 0.f));
                }
        }
    } else {
        #pragma unroll
        for (int ni = 0; ni < 4; ++ni) {
            const int nn = nt * BN + wn + ni * 16 + (lane & 15);
            #pragma unroll
            for (int mi = 0; mi < 4; ++mi)
                #pragma unroll
                for (int r = 0; r < 4; ++r) {
                    const int sl = wm + mi * 16 + ((lane >> 4) << 2) + r;
                    yout[((size_t)kb * PADROWS + row0 + sl) * NOUT + nn] = acc[mi][ni][r];
                }
        }
    }
}

// ------- Combine -------
__global__ __launch_bounds__(256)
void combine_kernel(const float* __restrict__ ypart, const float* __restrict__ b2,
                    const float* __restrict__ x, const int* __restrict__ offs_pad,
                    const int4* __restrict__ info, const float2* __restrict__ gpair,
                    float* __restrict__ out) {
    const int n = blockIdx.x, d = threadIdx.x * 4;
    const int4 ii = info[n];
    const float2 g = gpair[n];
    const int r1 = offs_pad[ii.x] + ii.y, r2 = offs_pad[ii.z] + ii.w;
    f32x4 y1 = {}, y2 = {};
    #pragma unroll
    for (int kb = 0; kb < KSPL; ++kb) {
        y1 += *(const f32x4*)(ypart + ((size_t)kb * PADROWS + r1) * DMODEL + d);
        y2 += *(const f32x4*)(ypart + ((size_t)kb * PADROWS + r2) * DMODEL + d);
    }
    const f32x4 b21 = *(const f32x4*)(b2 + (size_t)ii.x * DMODEL + d);
    const f32x4 b22 = *(const f32x4*)(b2 + (size_t)ii.z * DMODEL + d);
    const f32x4 xv  = *(const f32x4*)(x + (size_t)n * DMODEL + d);
    f32x4 o = g.x * (y1 + b21 + xv) + g.y * (y2 + b22 + xv);
    *(f32x4*)(out + (size_t)n * DMODEL + d) = o;
}

extern "C" void kernel_launch(void* const* d_in, const int* in_sizes, int n_in,
                              void* d_out, int out_size, void* d_ws, size_t ws_size,
                              hipStream_t stream) {
    const float* x      = (const float*)d_in[0];
    const float* gate_w = (const float*)d_in[1];
    const float* ln_g   = (const float*)d_in[2];
    const float* ln_b   = (const float*)d_in[3];
    const float* w1     = (const float*)d_in[4];
    const float* b1     = (const float*)d_in[5];
    const float* w2     = (const float*)d_in[6];
    const float* b2     = (const float*)d_in[7];
    float* out = (float*)d_out;

    char* w = (char*)d_ws;
    int*    cnt      = (int*)(w + 0);
    int*    offs_pad = (int*)(w + 64);
    int*    ntiles   = (int*)(w + 128);
    int4*   tilemap  = (int4*)(w + 192);
    int*    lists    = (int*)(w + 1024);
    float*  scores   = (float*)(w + 66560);
    int4*   info     = (int4*)(w + 132096);
    float2* gpair    = (float2*)(w + 164864);
    ushort* norm     = (ushort*)(w + 181248);
    ushort* A1       = (ushort*)(w + 4375552);
    ushort* h        = (ushort*)(w + 14861312);
    float*  ypart    = (float*)(w + 56804352);

    hipMemsetAsync(cnt, 0, 64, stream);

    router_kernel<<<N_TOK, 256, 0, stream>>>(x, gate_w, norm, scores, cnt, lists, info, gpair);
    prep_kernel<<<1, 256, 0, stream>>>(scores, cnt, offs_pad, ntiles, tilemap,
                                       out + (size_t)N_TOK * DMODEL);
    gather_kernel<<<PADROWS, 256, 0, stream>>>(norm, ln_g, ln_b, offs_pad, cnt, lists, A1);
    moe_gemm<DMODEL, FFDIM / BN, 1, true><<<TMAX * (FFDIM / BN), 256, 0, stream>>>(
        A1, w1, b1, ntiles, tilemap, h, nullptr);
    moe_gemm<FFDIM, DMODEL / BN, KSPL, false><<<TMAX * (DMODEL / BN) * KSPL, 256, 0, stream>>>(
        h, w2, nullptr, ntiles, tilemap, nullptr, ypart);
    combine_kernel<<<N_TOK, 256, 0, stream>>>(ypart, b2, x, offs_pad, info, gpair, out);
}